// Round 5
// baseline (242.596 us; speedup 1.0000x reference)
//
#include <hip/hip_runtime.h>

#define B_ 2
#define N_ 192
#define DIM_ 512
#define H_ 8
#define DH_ 64
#define EPS_RMS 1.1920929e-7f
#define QSC 0.18033688011112042f   // 0.125 * log2(e)  (logits in base-2)
#define ARR_ (B_*H_*N_*DH_)        // 196608

typedef float v4f __attribute__((ext_vector_type(4)));
typedef short v8s __attribute__((ext_vector_type(8)));

// ---------- helpers ----------
__device__ __forceinline__ unsigned int cvtpk(float a, float b) {
  unsigned int d;
  asm("v_cvt_pk_bf16_f32 %0, %1, %2" : "=v"(d) : "v"(a), "v"(b));
  return d;
}
__device__ __forceinline__ float bf16_lo(unsigned int u) { return __uint_as_float(u << 16); }
__device__ __forceinline__ float bf16_hi(unsigned int u) { return __uint_as_float(u & 0xffff0000u); }

// exp2: MUST go through the builtin so the compiler's hazard recognizer
// inserts the required trans-op wait state before VALU consumers.
// (R4 regression: raw inline-asm v_exp_f32 -> stale-VGPR read -> NaN.)
#if __has_builtin(__builtin_amdgcn_exp2f)
__device__ __forceinline__ float fexp2(float x) { return __builtin_amdgcn_exp2f(x); }
#else
__device__ __forceinline__ float fexp2(float x) {
  float r; asm("v_exp_f32 %0, %1\n\ts_nop 1" : "=v"(r) : "v"(x)); return r;
}
#endif

__device__ __forceinline__ v4f mfma16(uint4 a, uint4 b, v4f c) {
  union { uint4 u; v8s s; } ua, ub;
  ua.u = a; ub.u = b;
  return __builtin_amdgcn_mfma_f32_16x16x32_bf16(ua.s, ub.s, c, 0, 0, 0);
}

__device__ __forceinline__ void split8(const float* s, uint4& hi, uint4& lo) {
  float4 f0 = *(const float4*)s;
  float4 f1 = *(const float4*)(s + 4);
  hi.x = cvtpk(f0.x, f0.y); hi.y = cvtpk(f0.z, f0.w);
  hi.z = cvtpk(f1.x, f1.y); hi.w = cvtpk(f1.z, f1.w);
  lo.x = cvtpk(f0.x - bf16_lo(hi.x), f0.y - bf16_hi(hi.x));
  lo.y = cvtpk(f0.z - bf16_lo(hi.y), f0.w - bf16_hi(hi.y));
  lo.z = cvtpk(f1.x - bf16_lo(hi.z), f1.y - bf16_hi(hi.z));
  lo.w = cvtpk(f1.z - bf16_lo(hi.w), f1.w - bf16_hi(hi.w));
}

// ---------- Kernel 0: prepack tokens -> frag-ordered hi/lo bf16 ----------
// A-frag layout for 32-row tiles: uint4 at [((mt*8 + kc)*8 + g)*32 + m],
// element e = column kc*64 + g*8 + e, row = mt*32 + m.
__global__ __launch_bounds__(256)
void prepack_kernel(const float* __restrict__ tokens,
                    unsigned short* __restrict__ AtkHi, unsigned short* __restrict__ AtkLo)
{
  int idx = blockIdx.x * 256 + threadIdx.x;      // < 384*64 = 24576
  int token = idx >> 6, grp = idx & 63;
  int kc = grp >> 3, g = grp & 7;
  const float* s = tokens + (size_t)token*DIM_ + kc*64 + g*8;
  uint4 hi, lo; split8(s, hi, lo);
  int o = (((token >> 5)*8 + kc)*8 + g)*32 + (token & 31);
  ((uint4*)AtkHi)[o] = hi;
  ((uint4*)AtkLo)[o] = lo;
}

// ---------- Kernel 1: QKV GEMM (split-bf16 MFMA) + RMSNorm ----------
// grid (40, 12). A (tokens) from prepacked global frags; B (w_qkv) split in LDS.
// Q/K1/V1 written as fp32 planes; K2/V2 written directly in attn's packed B-frag order.
__global__ __launch_bounds__(256, 2)
void qkv_mfma_kernel(const unsigned short* __restrict__ AtkHi,
                     const unsigned short* __restrict__ AtkLo,
                     const float* __restrict__ w_qkv,
                     const float* __restrict__ qw, const float* __restrict__ k1w,
                     const float* __restrict__ k2w, const float* __restrict__ v1w,
                     const float* __restrict__ v2w,
                     float* __restrict__ Q, float* __restrict__ K1, float* __restrict__ V1,
                     uint4* __restrict__ K2P, uint4* __restrict__ V2P)
{
  const int bn = blockIdx.x;   // 0..39
  const int bm = blockIdx.y;   // 0..11
  const int tid = threadIdx.x;
  const int w = tid >> 6, l = tid & 63;
  const int c = l & 15, q = l >> 4;
  const int mhalf = w & 1, nhalf = w >> 1;

  __shared__ __align__(16) uint4 Bhi[8*64], Blo[8*64];   // 8KB each
  __shared__ float red[32][2];

  const uint4* AtkHiU = (const uint4*)AtkHi;
  const uint4* AtkLoU = (const uint4*)AtkLo;

  v4f acc[2] = {(v4f){0,0,0,0}, (v4f){0,0,0,0}};

  for (int kc = 0; kc < 8; ++kc) {
    const int k0 = kc * 64;
    #pragma unroll
    for (int cc = 0; cc < 2; ++cc) {
      int e = tid + 256*cc;
      int n = e >> 3, g = e & 7;
      uint4 hi, lo;
      split8(w_qkv + (size_t)(bn*64 + n)*DIM_ + k0 + g*8, hi, lo);
      Bhi[g*64 + (n ^ g)] = hi;
      Blo[g*64 + (n ^ g)] = lo;
    }
    __syncthreads();
    #pragma unroll
    for (int kh = 0; kh < 2; ++kh) {
      int g = kh*4 + q;
      uint4 ah = AtkHiU[((bm*8 + kc)*8 + g)*32 + mhalf*16 + c];
      uint4 al = AtkLoU[((bm*8 + kc)*8 + g)*32 + mhalf*16 + c];
      #pragma unroll
      for (int nt = 0; nt < 2; ++nt) {
        int n = nhalf*32 + nt*16 + c;
        uint4 bh = Bhi[g*64 + (n ^ g)];
        uint4 bl = Blo[g*64 + (n ^ g)];
        acc[nt] = mfma16(ah, bh, acc[nt]);
        acc[nt] = mfma16(ah, bl, acc[nt]);
        acc[nt] = mfma16(al, bh, acc[nt]);
      }
    }
    __syncthreads();
  }

  // RMSNorm row sums (D-layout: col = nhalf*32+nt*16+c, row = mhalf*16+q*4+r)
  float ss[4];
  #pragma unroll
  for (int r = 0; r < 4; ++r) {
    ss[r] = acc[0][r]*acc[0][r] + acc[1][r]*acc[1][r];
    #pragma unroll
    for (int off = 1; off < 16; off <<= 1) ss[r] += __shfl_xor(ss[r], off, 64);
  }
  if (c == 0) {
    #pragma unroll
    for (int r = 0; r < 4; ++r) red[mhalf*16 + q*4 + r][nhalf] = ss[r];
  }
  __syncthreads();

  // classify destination
  const float* nw; float* dstPlane = nullptr; int hh; bool isK2 = false, isV2 = false;
  if (bn < 8)       { nw = qw; dstPlane = Q; hh = bn; }
  else if (bn < 24) { int g = bn - 8;  hh = g >> 1;
                      if (g & 1) { nw = k2w; isK2 = true; } else { nw = k1w; dstPlane = K1; } }
  else              { int g = bn - 24; hh = g >> 1;
                      if (g & 1) { nw = v2w; isV2 = true; } else { nw = v1w; dstPlane = V1; } }

  const int b = (bm >= 6) ? 1 : 0;
  const int bmm = bm - b*6;          // token tile within batch
  const int bh = b*8 + hh;

  float sc[4];
  #pragma unroll
  for (int r = 0; r < 4; ++r) {
    int row = mhalf*16 + q*4 + r;
    float sst = red[row][0] + red[row][1];
    sc[r] = rsqrtf(sst * (1.0f/64.0f) + EPS_RMS);
  }

  if (dstPlane) {
    #pragma unroll
    for (int r = 0; r < 4; ++r) {
      int row = mhalf*16 + q*4 + r;
      int n = bmm*32 + row;
      size_t obase = (((size_t)bh)*N_ + n)*DH_;
      #pragma unroll
      for (int nt = 0; nt < 2; ++nt) {
        int d = nhalf*32 + nt*16 + c;
        dstPlane[obase + d] = acc[nt][r] * sc[r] * nw[d];
      }
    }
  } else {
    // write normalized fp32 into LDS tile [32 tok][64 d], then pack to frag order
    float* tile = (float*)Bhi;       // 8KB, dead after main loop
    #pragma unroll
    for (int r = 0; r < 4; ++r) {
      int row = mhalf*16 + q*4 + r;
      #pragma unroll
      for (int nt = 0; nt < 2; ++nt) {
        int d = nhalf*32 + nt*16 + c;
        tile[row*64 + d] = acc[nt][r] * sc[r] * nw[d];
      }
    }
    __syncthreads();
    if (isK2) {
      // B-frag: lane ll: kcol = nt*16+(ll&15), k=d = ks*32+(ll>>4)*8+e
      int ntl = tid >> 7, ks2 = (tid >> 6) & 1, ll = tid & 63;
      int tok = ntl*16 + (ll & 15);
      int d0 = ks2*32 + ((ll >> 4) << 3);
      const float* sp = tile + tok*64 + d0;
      uint4 wv;
      wv.x = cvtpk(sp[0], sp[1]); wv.y = cvtpk(sp[2], sp[3]);
      wv.z = cvtpk(sp[4], sp[5]); wv.w = cvtpk(sp[6], sp[7]);
      K2P[(size_t)bh*1536 + ((bmm*2 + ntl)*2 + ks2)*64 + ll] = wv;
    } else {
      // V2 B-frag: lane ll: d = nt*16+(ll&15), k=kcol = ks*32+(ll>>4)*8+e
      int ntd = tid >> 6, ll = tid & 63;
      int dd = ntd*16 + (ll & 15);
      int t0 = (ll >> 4) << 3;
      uint4 wv;
      wv.x = cvtpk(tile[(t0+0)*64 + dd], tile[(t0+1)*64 + dd]);
      wv.y = cvtpk(tile[(t0+2)*64 + dd], tile[(t0+3)*64 + dd]);
      wv.z = cvtpk(tile[(t0+4)*64 + dd], tile[(t0+5)*64 + dd]);
      wv.w = cvtpk(tile[(t0+6)*64 + dd], tile[(t0+7)*64 + dd]);
      V2P[(size_t)bh*1536 + (ntd*6 + bmm)*64 + ll] = wv;
    }
  }
}

// ---------- Kernel 2: two-simplicial attention (S^T trick, packed staging) ----------
// grid 768: bid -> bh = bid/48, i0 = (bid%48)*4. 4 waves, wave w owns j in [48w,48w+48).
// S^T = mfma(A=K2frag, B=K1.*q) -> lane holds 4 consecutive kcols of row j=c ->
// P written as 2x b64 per (jt,mt), read back as one b128 A-frag. 3 wg/CU.
__global__ __launch_bounds__(256, 3)
void attn_kernel(const float* __restrict__ Qg, const float* __restrict__ K1g,
                 const float* __restrict__ V1g,
                 const uint4* __restrict__ K2P, const uint4* __restrict__ V2P,
                 unsigned short* __restrict__ ATThi, unsigned short* __restrict__ ATTlo)
{
  __shared__ __align__(16) unsigned char lds[54272];
  // K2B [0,24576) | V2B [24576,49152) | P 4x1KB [49152,53248) | redF [53248,54272)
  uint4* K2B  = (uint4*)(lds);
  uint4* V2B  = (uint4*)(lds + 24576);
  float* redF = (float*)(lds + 53248);

  const int tid = threadIdx.x;
  const int w = tid >> 6, l = tid & 63;
  const int c = l & 15, q = l >> 4;
  const int bid = blockIdx.x;
  const int bh = bid / 48;
  const int sub = bid - bh*48;
  const int b = bh >> 3, h = bh & 7;
  const int i0 = sub * 4;
  const size_t base = (size_t)bh * (N_ * DH_);

  // flat copy of packed K2/V2 into LDS (no conversion)
  {
    const uint4* s2 = K2P + (size_t)bh*1536;
    const uint4* s3 = V2P + (size_t)bh*1536;
    #pragma unroll
    for (int t = 0; t < 6; ++t) K2B[tid + 256*t] = s2[tid + 256*t];
    #pragma unroll
    for (int t = 0; t < 6; ++t) V2B[tid + 256*t] = s3[tid + 256*t];
  }

  // K1 rows in registers (A/B-frag order): j = w*48+jt*16+c, d = ks*32+q*8+e
  unsigned int k1p[6][4];
  #pragma unroll
  for (int jt = 0; jt < 3; ++jt)
    #pragma unroll
    for (int ks = 0; ks < 2; ++ks) {
      int j = w*48 + jt*16 + c;
      int d0 = ks*32 + (q << 3);
      const float* s = K1g + base + (size_t)j*64 + d0;
      float4 f0 = *(const float4*)s;
      float4 f1 = *(const float4*)(s + 4);
      k1p[jt*2+ks][0] = cvtpk(f0.x, f0.y);
      k1p[jt*2+ks][1] = cvtpk(f0.z, f0.w);
      k1p[jt*2+ks][2] = cvtpk(f1.x, f1.y);
      k1p[jt*2+ks][3] = cvtpk(f1.z, f1.w);
    }
  // V1 in registers (D-layout order): rows j = w*48+jt*16+q*4+.., col d = dt*16+c
  unsigned int v1p[12][2];
  #pragma unroll
  for (int jt = 0; jt < 3; ++jt)
    #pragma unroll
    for (int dt = 0; dt < 4; ++dt) {
      int jb = w*48 + jt*16 + q*4;
      int d = dt*16 + c;
      const float* s = V1g + base + (size_t)jb*64 + d;
      v1p[jt*4+dt][0] = cvtpk(s[0],   s[64]);
      v1p[jt*4+dt][1] = cvtpk(s[128], s[192]);
    }

  __syncthreads();

  unsigned char* Pw = lds + 49152 + w*1024;   // wave-private 1KB P tile (16 j x 32 kcol bf16)
  const int wG = (q ^ (c & 3)) << 4;          // swizzled read group offset

  for (int ii = 0; ii < 4; ++ii) {
    // q fragment (pre-scaled), read directly from Q plane
    float qv[2][8];
    #pragma unroll
    for (int ks = 0; ks < 2; ++ks) {
      const float* s = Qg + base + (size_t)(i0 + ii)*64 + ks*32 + (q << 3);
      float4 a = *(const float4*)s;
      float4 bq = *(const float4*)(s + 4);
      qv[ks][0]=a.x*QSC;  qv[ks][1]=a.y*QSC;  qv[ks][2]=a.z*QSC;  qv[ks][3]=a.w*QSC;
      qv[ks][4]=bq.x*QSC; qv[ks][5]=bq.y*QSC; qv[ks][6]=bq.z*QSC; qv[ks][7]=bq.w*QSC;
    }
    // B-frags: (K1 .* q_scaled) -> bf16
    uint4 afr[3][2];
    #pragma unroll
    for (int jt = 0; jt < 3; ++jt)
      #pragma unroll
      for (int ks = 0; ks < 2; ++ks) {
        unsigned int wds[4];
        #pragma unroll
        for (int e = 0; e < 4; ++e) {
          float lo = bf16_lo(k1p[jt*2+ks][e]) * qv[ks][2*e];
          float hi = bf16_hi(k1p[jt*2+ks][e]) * qv[ks][2*e+1];
          wds[e] = cvtpk(lo, hi);
        }
        afr[jt][ks].x = wds[0]; afr[jt][ks].y = wds[1];
        afr[jt][ks].z = wds[2]; afr[jt][ks].w = wds[3];
      }

    v4f racc[3][4];
    #pragma unroll
    for (int jt = 0; jt < 3; ++jt)
      #pragma unroll
      for (int dt = 0; dt < 4; ++dt)
        racc[jt][dt] = (v4f){0.f, 0.f, 0.f, 0.f};
    float psum = 0.f;

    for (int ch = 0; ch < 6; ++ch) {
      uint4 kb[2][2];
      #pragma unroll
      for (int mt = 0; mt < 2; ++mt)
        #pragma unroll
        for (int ks = 0; ks < 2; ++ks)
          kb[mt][ks] = K2B[((ch*2 + mt)*2 + ks)*64 + l];
      uint4 vb[4];
      #pragma unroll
      for (int dt = 0; dt < 4; ++dt)
        vb[dt] = V2B[(dt*6 + ch)*64 + l];

      #pragma unroll
      for (int jt = 0; jt < 3; ++jt) {
        // S^T: D rows = kcol (mt*16+q*4+r), col = j = c
        #pragma unroll
        for (int mt = 0; mt < 2; ++mt) {
          v4f z = (v4f){0.f, 0.f, 0.f, 0.f};
          z = mfma16(kb[mt][0], afr[jt][0], z);
          z = mfma16(kb[mt][1], afr[jt][1], z);
          float p0 = fexp2(z[0]), p1 = fexp2(z[1]), p2 = fexp2(z[2]), p3 = fexp2(z[3]);
          psum += (p0 + p1) + (p2 + p3);
          uint2 pwv; pwv.x = cvtpk(p0, p1); pwv.y = cvtpk(p2, p3);
          int G = ((mt*2 + (q >> 1)) ^ (c & 3)) << 4;
          *(uint2*)(Pw + c*64 + G + ((q & 1) << 3)) = pwv;
        }
        uint4 pa = *(uint4*)(Pw + c*64 + wG);
        #pragma unroll
        for (int dt = 0; dt < 4; ++dt)
          racc[jt][dt] = mfma16(pa, vb[dt], racc[jt][dt]);
      }
    }

    // softmax denominator: wave sum then cross-wave via P region (dead now)
    float lsum = psum;
    #pragma unroll
    for (int off = 32; off; off >>= 1) lsum += __shfl_xor(lsum, off, 64);

    // out partials: op[dt] = sum over this wave's j of V1[j,d]*R[j,d]
    float op[4] = {0.f, 0.f, 0.f, 0.f};
    #pragma unroll
    for (int jt = 0; jt < 3; ++jt)
      #pragma unroll
      for (int dt = 0; dt < 4; ++dt) {
        op[dt] = fmaf(bf16_lo(v1p[jt*4+dt][0]), racc[jt][dt][0], op[dt]);
        op[dt] = fmaf(bf16_hi(v1p[jt*4+dt][0]), racc[jt][dt][1], op[dt]);
        op[dt] = fmaf(bf16_lo(v1p[jt*4+dt][1]), racc[jt][dt][2], op[dt]);
        op[dt] = fmaf(bf16_hi(v1p[jt*4+dt][1]), racc[jt][dt][3], op[dt]);
      }
    #pragma unroll
    for (int dt = 0; dt < 4; ++dt) {
      op[dt] += __shfl_xor(op[dt], 16, 64);
      op[dt] += __shfl_xor(op[dt], 32, 64);
    }
    if (l < 16) {
      #pragma unroll
      for (int dt = 0; dt < 4; ++dt) redF[w*64 + dt*16 + l] = op[dt];
    }
    if (l == 0) *(float*)(lds + 49152 + w*1024) = lsum;
    __syncthreads();
    if (tid < 64) {
      float o = redF[tid] + redF[64 + tid] + redF[128 + tid] + redF[192 + tid];
      float lt = *(float*)(lds + 49152) + *(float*)(lds + 49152 + 1024)
               + *(float*)(lds + 49152 + 2048) + *(float*)(lds + 49152 + 3072);
      float v = o / lt;
      // write ATT directly in out_proj's A-frag hi/lo order
      int m_tok = b*N_ + i0 + ii;
      int mt = m_tok >> 5, mloc = m_tok & 31;
      int g = tid >> 3, e = tid & 7;
      int off = ((((mt*8 + h)*8 + g)*32 + mloc) << 3) + e;
      unsigned short hs = (unsigned short)cvtpk(v, v);
      float resid = v - __uint_as_float(((unsigned int)hs) << 16);
      unsigned short lsb = (unsigned short)cvtpk(resid, resid);
      ATThi[off] = hs; ATTlo[off] = lsb;
    }
    __syncthreads();
  }
}

// ---------- Kernel 3: output projection (A prepacked by attn, B split in LDS) ----------
// grid (8, 12)
__global__ __launch_bounds__(256, 2)
void out_proj_kernel(const unsigned short* __restrict__ ATThi,
                     const unsigned short* __restrict__ ATTlo,
                     const float* __restrict__ w_out, float* __restrict__ out)
{
  const int bn = blockIdx.x;   // 0..7
  const int bm = blockIdx.y;   // 0..11
  const int tid = threadIdx.x;
  const int w = tid >> 6, l = tid & 63;
  const int c = l & 15, q = l >> 4;
  const int mhalf = w & 1, nhalf = w >> 1;

  __shared__ __align__(16) uint4 Bhi[8*64], Blo[8*64];

  const uint4* AHi = (const uint4*)ATThi;
  const uint4* ALo = (const uint4*)ATTlo;

  v4f acc[2] = {(v4f){0,0,0,0}, (v4f){0,0,0,0}};

  for (int kc = 0; kc < 8; ++kc) {
    const int k0 = kc * 64;
    #pragma unroll
    for (int cc = 0; cc < 2; ++cc) {
      int e = tid + 256*cc;
      int n = e >> 3, g = e & 7;
      uint4 hi, lo;
      split8(w_out + (size_t)(bn*64 + n)*DIM_ + k0 + g*8, hi, lo);
      Bhi[g*64 + (n ^ g)] = hi;
      Blo[g*64 + (n ^ g)] = lo;
    }
    __syncthreads();
    #pragma unroll
    for (int kh = 0; kh < 2; ++kh) {
      int g = kh*4 + q;
      uint4 ah = AHi[((bm*8 + kc)*8 + g)*32 + mhalf*16 + c];
      uint4 al = ALo[((bm*8 + kc)*8 + g)*32 + mhalf*16 + c];
      #pragma unroll
      for (int nt = 0; nt < 2; ++nt) {
        int n = nhalf*32 + nt*16 + c;
        uint4 bh = Bhi[g*64 + (n ^ g)];
        uint4 bl = Blo[g*64 + (n ^ g)];
        acc[nt] = mfma16(ah, bh, acc[nt]);
        acc[nt] = mfma16(ah, bl, acc[nt]);
        acc[nt] = mfma16(al, bh, acc[nt]);
      }
    }
    __syncthreads();
  }

  #pragma unroll
  for (int r = 0; r < 4; ++r) {
    int m = bm*32 + mhalf*16 + q*4 + r;
    #pragma unroll
    for (int nt = 0; nt < 2; ++nt) {
      int d = nhalf*32 + nt*16 + c;
      out[(size_t)m*DIM_ + bn*64 + d] = acc[nt][r];
    }
  }
}

// ---------- launch ----------
extern "C" void kernel_launch(void* const* d_in, const int* in_sizes, int n_in,
                              void* d_out, int out_size, void* d_ws, size_t ws_size,
                              hipStream_t stream) {
  const float* tokens = (const float*)d_in[0];
  const float* w_qkv  = (const float*)d_in[1];
  const float* w_out  = (const float*)d_in[2];
  const float* qw     = (const float*)d_in[3];
  const float* k1w    = (const float*)d_in[4];
  const float* k2w    = (const float*)d_in[5];
  const float* v1w    = (const float*)d_in[6];
  const float* v2w    = (const float*)d_in[7];
  float* out = (float*)d_out;

  float* ws = (float*)d_ws;
  // ws layout (floats): Q | K1 | V1 | K2P(98304) | V2P(98304) | AtkHi/ATThi(98304) | AtkLo/ATTlo(98304)
  float* Q   = ws;
  float* K1  = ws + (size_t)ARR_;
  float* V1  = ws + (size_t)2*ARR_;
  uint4* K2P = (uint4*)(ws + (size_t)3*ARR_);
  uint4* V2P = (uint4*)(ws + (size_t)3*ARR_ + 98304);
  unsigned short* AtkHi = (unsigned short*)(ws + (size_t)3*ARR_ + 2*98304);
  unsigned short* AtkLo = (unsigned short*)(ws + (size_t)3*ARR_ + 3*98304);
  // ATT packed aliases tokens-packed region (dead after qkv)
  unsigned short* ATThi = AtkHi;
  unsigned short* ATTlo = AtkLo;

  prepack_kernel<<<96, 256, 0, stream>>>(tokens, AtkHi, AtkLo);
  qkv_mfma_kernel<<<dim3(40, 12), 256, 0, stream>>>(AtkHi, AtkLo, w_qkv,
                                                    qw, k1w, k2w, v1w, v2w,
                                                    Q, K1, V1, K2P, V2P);
  attn_kernel<<<768, 256, 0, stream>>>(Q, K1, V1, K2P, V2P, ATThi, ATTlo);
  out_proj_kernel<<<dim3(8, 12), 256, 0, stream>>>(ATThi, ATTlo, w_out, out);
}

// Round 7
// 129.364 us; speedup vs baseline: 1.8753x; 1.8753x over previous
//
#include <hip/hip_runtime.h>

// R7 = R6 resubmission (R6 bench was an infra failure: container died twice,
// no kernel signal). Source audited for bounds/hang safety; unchanged logic.

#define B_ 2
#define N_ 192
#define DIM_ 512
#define H_ 8
#define DH_ 64
#define EPS_RMS 1.1920929e-7f
#define QSC 0.18033688011112042f   // 0.125 * log2(e)  (logits in base-2)
#define ARR_ (B_*H_*N_*DH_)        // 196608

typedef float v4f __attribute__((ext_vector_type(4)));
typedef short v8s __attribute__((ext_vector_type(8)));

// ---------- helpers ----------
__device__ __forceinline__ unsigned int cvtpk(float a, float b) {
  unsigned int d;
  asm("v_cvt_pk_bf16_f32 %0, %1, %2" : "=v"(d) : "v"(a), "v"(b));
  return d;
}
__device__ __forceinline__ float bf16_lo(unsigned int u) { return __uint_as_float(u << 16); }
__device__ __forceinline__ float bf16_hi(unsigned int u) { return __uint_as_float(u & 0xffff0000u); }

// exp2 via builtin ONLY (R4 lesson: raw inline-asm v_exp_f32 lacks the
// trans-op hazard wait -> stale VGPR -> NaN).
#if __has_builtin(__builtin_amdgcn_exp2f)
__device__ __forceinline__ float fexp2(float x) { return __builtin_amdgcn_exp2f(x); }
#else
__device__ __forceinline__ float fexp2(float x) {
  float r; asm("v_exp_f32 %0, %1\n\ts_nop 1" : "=v"(r) : "v"(x)); return r;
}
#endif

__device__ __forceinline__ v4f mfma16(uint4 a, uint4 b, v4f c) {
  union { uint4 u; v8s s; } ua, ub;
  ua.u = a; ub.u = b;
  return __builtin_amdgcn_mfma_f32_16x16x32_bf16(ua.s, ub.s, c, 0, 0, 0);
}

__device__ __forceinline__ void split8(const float* s, uint4& hi, uint4& lo) {
  float4 f0 = *(const float4*)s;
  float4 f1 = *(const float4*)(s + 4);
  hi.x = cvtpk(f0.x, f0.y); hi.y = cvtpk(f0.z, f0.w);
  hi.z = cvtpk(f1.x, f1.y); hi.w = cvtpk(f1.z, f1.w);
  lo.x = cvtpk(f0.x - bf16_lo(hi.x), f0.y - bf16_hi(hi.x));
  lo.y = cvtpk(f0.z - bf16_lo(hi.y), f0.w - bf16_hi(hi.y));
  lo.z = cvtpk(f1.x - bf16_lo(hi.z), f1.y - bf16_hi(hi.z));
  lo.w = cvtpk(f1.z - bf16_lo(hi.w), f1.w - bf16_hi(hi.w));
}

// ---------- Kernel 0: prepack tokens + w_qkv + w_out -> frag-ordered hi/lo bf16 ----------
// tokens: 32-row tiles, o = ((mt*8+kc)*8+g)*32 + m
// weights: 64-row tiles, o = ((bt*8+kc)*8+g)*64 + r
__global__ __launch_bounds__(256)
void prepack_kernel(const float* __restrict__ tokens, const float* __restrict__ w_qkv,
                    const float* __restrict__ w_out,
                    uint4* __restrict__ AtkHi, uint4* __restrict__ AtkLo,
                    uint4* __restrict__ WqHi,  uint4* __restrict__ WqLo,
                    uint4* __restrict__ WoHi,  uint4* __restrict__ WoLo)
{
  int idx = blockIdx.x * 256 + threadIdx.x;     // < 221184
  const float* src; uint4 *dh, *dl; int o;
  if (idx < 24576) {
    int token = idx >> 6, kc = (idx >> 3) & 7, g = idx & 7;
    src = tokens + (size_t)token*DIM_ + kc*64 + g*8;
    o = (((token >> 5)*8 + kc)*8 + g)*32 + (token & 31);
    dh = AtkHi; dl = AtkLo;
  } else if (idx < 188416) {
    int t = idx - 24576;
    int row = t >> 6, kc = (t >> 3) & 7, g = t & 7;
    src = w_qkv + (size_t)row*DIM_ + kc*64 + g*8;
    o = (((row >> 6)*8 + kc)*8 + g)*64 + (row & 63);
    dh = WqHi; dl = WqLo;
  } else {
    int t = idx - 188416;
    int row = t >> 6, kc = (t >> 3) & 7, g = t & 7;
    src = w_out + (size_t)row*DIM_ + kc*64 + g*8;
    o = (((row >> 6)*8 + kc)*8 + g)*64 + (row & 63);
    dh = WoHi; dl = WoLo;
  }
  uint4 hi, lo; split8(src, hi, lo);
  dh[o] = hi; dl[o] = lo;
}

// ---------- Kernel 1: QKV GEMM (split-bf16 MFMA, barrier-free K loop) + RMSNorm ----------
// grid (40, 12). A and B both prepacked in global; epilogue packs K1/K2/V1/V2
// directly into attn's consumption layouts; Q stays fp32.
__global__ __launch_bounds__(256)
void qkv_mfma_kernel(const uint4* __restrict__ AtkHi, const uint4* __restrict__ AtkLo,
                     const uint4* __restrict__ WqHi,  const uint4* __restrict__ WqLo,
                     const float* __restrict__ qw, const float* __restrict__ k1w,
                     const float* __restrict__ k2w, const float* __restrict__ v1w,
                     const float* __restrict__ v2w,
                     float* __restrict__ Q,
                     uint4* __restrict__ K1P, uint2* __restrict__ V1P,
                     uint4* __restrict__ K2P, uint4* __restrict__ V2P)
{
  const int bn = blockIdx.x;   // 0..39 (64 rows of w_qkv)
  const int bm = blockIdx.y;   // 0..11 (32 tokens)
  const int tid = threadIdx.x;
  const int w = tid >> 6, l = tid & 63;
  const int c = l & 15, q = l >> 4;
  const int mhalf = w & 1, nhalf = w >> 1;

  __shared__ float tile[32*64];     // 8KB, epilogue only
  __shared__ float red[32][2];

  v4f acc[2] = {(v4f){0,0,0,0}, (v4f){0,0,0,0}};

  for (int kc = 0; kc < 8; ++kc) {
    #pragma unroll
    for (int kh = 0; kh < 2; ++kh) {
      int g = kh*4 + q;
      int aidx = ((bm*8 + kc)*8 + g)*32 + mhalf*16 + c;
      uint4 ah = AtkHi[aidx];
      uint4 al = AtkLo[aidx];
      #pragma unroll
      for (int nt = 0; nt < 2; ++nt) {
        int bidx = ((bn*8 + kc)*8 + g)*64 + nhalf*32 + nt*16 + c;
        uint4 bh = WqHi[bidx];
        uint4 bl = WqLo[bidx];
        acc[nt] = mfma16(ah, bh, acc[nt]);
        acc[nt] = mfma16(ah, bl, acc[nt]);
        acc[nt] = mfma16(al, bh, acc[nt]);
      }
    }
  }

  // RMSNorm row sums (D layout: col = nhalf*32+nt*16+c, row = mhalf*16+q*4+r)
  float ss[4];
  #pragma unroll
  for (int r = 0; r < 4; ++r) {
    ss[r] = acc[0][r]*acc[0][r] + acc[1][r]*acc[1][r];
    #pragma unroll
    for (int off = 1; off < 16; off <<= 1) ss[r] += __shfl_xor(ss[r], off, 64);
  }
  if (c == 0) {
    #pragma unroll
    for (int r = 0; r < 4; ++r) red[mhalf*16 + q*4 + r][nhalf] = ss[r];
  }
  __syncthreads();

  // classify destination
  const float* nw; int hh; int kind;   // 0=Q 1=K1 2=K2 3=V1 4=V2
  if (bn < 8)       { nw = qw; hh = bn; kind = 0; }
  else if (bn < 24) { int g = bn - 8;  hh = g >> 1; kind = (g & 1) ? 2 : 1; nw = (g & 1) ? k2w : k1w; }
  else              { int g = bn - 24; hh = g >> 1; kind = (g & 1) ? 4 : 3; nw = (g & 1) ? v2w : v1w; }

  const int b = (bm >= 6) ? 1 : 0;
  const int bmm = bm - b*6;
  const int bh = b*8 + hh;

  float sc[4];
  #pragma unroll
  for (int r = 0; r < 4; ++r) {
    int row = mhalf*16 + q*4 + r;
    sc[r] = rsqrtf((red[row][0] + red[row][1]) * (1.0f/64.0f) + EPS_RMS);
  }

  if (kind == 0) {
    #pragma unroll
    for (int r = 0; r < 4; ++r) {
      int row = mhalf*16 + q*4 + r;
      size_t obase = (((size_t)bh)*N_ + bmm*32 + row)*DH_;
      #pragma unroll
      for (int nt = 0; nt < 2; ++nt) {
        int d = nhalf*32 + nt*16 + c;
        Q[obase + d] = acc[nt][r] * sc[r] * nw[d];
      }
    }
    return;
  }

  // normalized fp32 -> LDS tile [32 tok][64 d]
  #pragma unroll
  for (int r = 0; r < 4; ++r) {
    int row = mhalf*16 + q*4 + r;
    #pragma unroll
    for (int nt = 0; nt < 2; ++nt) {
      int d = nhalf*32 + nt*16 + c;
      tile[row*64 + d] = acc[nt][r] * sc[r] * nw[d];
    }
  }
  __syncthreads();

  if (kind == 1) {
    // K1 A/B-frag: uint4 per (jt_l, ks, lane): row j = jt_l*16+cc, d = ks*32+qq*8+e
    int jt_l = tid >> 7, ks = (tid >> 6) & 1, ll = tid & 63;
    int qq = ll >> 4, cc = ll & 15;
    const float* sp = tile + (jt_l*16 + cc)*64 + ks*32 + qq*8;
    uint4 wv;
    wv.x = cvtpk(sp[0], sp[1]); wv.y = cvtpk(sp[2], sp[3]);
    wv.z = cvtpk(sp[4], sp[5]); wv.w = cvtpk(sp[6], sp[7]);
    K1P[((bh*12 + bmm*2 + jt_l)*2 + ks)*64 + ll] = wv;
  } else if (kind == 2) {
    // K2 B-frag (attn S): kcol = tok, k = d
    int ntl = tid >> 7, ks2 = (tid >> 6) & 1, ll = tid & 63;
    int tok = ntl*16 + (ll & 15);
    int d0 = ks2*32 + ((ll >> 4) << 3);
    const float* sp = tile + tok*64 + d0;
    uint4 wv;
    wv.x = cvtpk(sp[0], sp[1]); wv.y = cvtpk(sp[2], sp[3]);
    wv.z = cvtpk(sp[4], sp[5]); wv.w = cvtpk(sp[6], sp[7]);
    K2P[(size_t)bh*1536 + ((bmm*2 + ntl)*2 + ks2)*64 + ll] = wv;
  } else if (kind == 3) {
    // V1 D-read order: uint2 per (jt_l, dt, lane): rows jt_l*16+qq*4+0..3, col dt*16+cc
    #pragma unroll
    for (int pass = 0; pass < 2; ++pass) {
      int e = tid + 256*pass;
      int jt_l = e >> 8, dt = (e >> 6) & 3, ll = e & 63;
      int qq = ll >> 4, cc = ll & 15;
      int r0 = jt_l*16 + qq*4;
      int d = dt*16 + cc;
      uint2 wv;
      wv.x = cvtpk(tile[r0*64 + d],       tile[(r0+1)*64 + d]);
      wv.y = cvtpk(tile[(r0+2)*64 + d],   tile[(r0+3)*64 + d]);
      V1P[((bh*12 + bmm*2 + jt_l)*4 + dt)*64 + ll] = wv;
    }
  } else {
    // V2 B-frag (attn PV): n = d, k = tok
    int ntd = tid >> 6, ll = tid & 63;
    int dd = ntd*16 + (ll & 15);
    int t0 = (ll >> 4) << 3;
    uint4 wv;
    wv.x = cvtpk(tile[(t0+0)*64 + dd], tile[(t0+1)*64 + dd]);
    wv.y = cvtpk(tile[(t0+2)*64 + dd], tile[(t0+3)*64 + dd]);
    wv.z = cvtpk(tile[(t0+4)*64 + dd], tile[(t0+5)*64 + dd]);
    wv.w = cvtpk(tile[(t0+6)*64 + dd], tile[(t0+7)*64 + dd]);
    V2P[(size_t)bh*1536 + (ntd*6 + bmm)*64 + ll] = wv;
  }
}

// ---------- Kernel 2: two-simplicial attention ----------
// grid 512: bh = bid>>5, i0 = (bid&31)*6. 4 waves, wave w owns j in [48w,48w+48).
// S^T = mfma(A=K2frag, B=K1.*q). P tile: WRITE-LINEAR layout, slot = mt*64+lane
// (uint2 per slot) -> sequential b64 writes (0 excess conflicts); A-frag read =
// two b64 at W0=(q>>1)*64+(q&1)*32+c and W0+16 (4 dwords/bank = floor).
__global__ __launch_bounds__(256, 2)
void attn_kernel(const float* __restrict__ Qg,
                 const uint4* __restrict__ K1Pg, const uint2* __restrict__ V1Pg,
                 const uint4* __restrict__ K2P,  const uint4* __restrict__ V2P,
                 unsigned short* __restrict__ ATThi, unsigned short* __restrict__ ATTlo)
{
  __shared__ __align__(16) unsigned char lds[54272];
  // K2B [0,24576) | V2B [24576,49152) | P 4x1KB [49152,53248) | redF [53248,54272)
  uint4* K2B  = (uint4*)(lds);
  uint4* V2B  = (uint4*)(lds + 24576);
  float* redF = (float*)(lds + 53248);

  const int tid = threadIdx.x;
  const int w = tid >> 6, l = tid & 63;
  const int c = l & 15, q = l >> 4;
  const int bid = blockIdx.x;
  const int bh = bid >> 5;
  const int sub = bid & 31;
  const int b = bh >> 3, h = bh & 7;
  const int i0 = sub * 6;
  const size_t base = (size_t)bh * (N_ * DH_);

  // flat copy of packed K2/V2 into LDS
  {
    const uint4* s2 = K2P + (size_t)bh*1536;
    const uint4* s3 = V2P + (size_t)bh*1536;
    #pragma unroll
    for (int t = 0; t < 6; ++t) K2B[tid + 256*t] = s2[tid + 256*t];
    #pragma unroll
    for (int t = 0; t < 6; ++t) V2B[tid + 256*t] = s3[tid + 256*t];
  }

  // K1 frags (bf16, prepacked): j = w*48+jt*16+c, d = ks*32+q*8+e
  uint4 k1f[6];
  #pragma unroll
  for (int jt = 0; jt < 3; ++jt)
    #pragma unroll
    for (int ks = 0; ks < 2; ++ks)
      k1f[jt*2+ks] = K1Pg[((bh*12 + w*3 + jt)*2 + ks)*64 + l];
  // V1 (bf16, prepacked D-read order)
  uint2 v1f[12];
  #pragma unroll
  for (int jt = 0; jt < 3; ++jt)
    #pragma unroll
    for (int dt = 0; dt < 4; ++dt)
      v1f[jt*4+dt] = V1Pg[((bh*12 + w*3 + jt)*4 + dt)*64 + l];

  __syncthreads();

  unsigned char* Pw = lds + 49152 + w*1024;   // wave-private P tile
  const int rbase = (((q >> 1) * 64 + (q & 1) * 32 + c)) << 3;

  for (int ii = 0; ii < 6; ++ii) {
    float qv[2][8];
    #pragma unroll
    for (int ks = 0; ks < 2; ++ks) {
      const float* s = Qg + base + (size_t)(i0 + ii)*64 + ks*32 + (q << 3);
      float4 a = *(const float4*)s;
      float4 bq = *(const float4*)(s + 4);
      qv[ks][0]=a.x*QSC;  qv[ks][1]=a.y*QSC;  qv[ks][2]=a.z*QSC;  qv[ks][3]=a.w*QSC;
      qv[ks][4]=bq.x*QSC; qv[ks][5]=bq.y*QSC; qv[ks][6]=bq.z*QSC; qv[ks][7]=bq.w*QSC;
    }
    // B-frags: (K1 .* q_scaled) -> bf16
    uint4 afr[3][2];
    #pragma unroll
    for (int jt = 0; jt < 3; ++jt)
      #pragma unroll
      for (int ks = 0; ks < 2; ++ks) {
        uint4 kf = k1f[jt*2+ks];
        afr[jt][ks].x = cvtpk(bf16_lo(kf.x)*qv[ks][0], bf16_hi(kf.x)*qv[ks][1]);
        afr[jt][ks].y = cvtpk(bf16_lo(kf.y)*qv[ks][2], bf16_hi(kf.y)*qv[ks][3]);
        afr[jt][ks].z = cvtpk(bf16_lo(kf.z)*qv[ks][4], bf16_hi(kf.z)*qv[ks][5]);
        afr[jt][ks].w = cvtpk(bf16_lo(kf.w)*qv[ks][6], bf16_hi(kf.w)*qv[ks][7]);
      }

    v4f racc[3][4];
    #pragma unroll
    for (int jt = 0; jt < 3; ++jt)
      #pragma unroll
      for (int dt = 0; dt < 4; ++dt)
        racc[jt][dt] = (v4f){0.f, 0.f, 0.f, 0.f};
    float psum = 0.f;

    for (int ch = 0; ch < 6; ++ch) {
      uint4 kb[2][2];
      #pragma unroll
      for (int mt = 0; mt < 2; ++mt)
        #pragma unroll
        for (int ks = 0; ks < 2; ++ks)
          kb[mt][ks] = K2B[((ch*2 + mt)*2 + ks)*64 + l];
      uint4 vb[4];
      #pragma unroll
      for (int dt = 0; dt < 4; ++dt)
        vb[dt] = V2B[(dt*6 + ch)*64 + l];

      #pragma unroll
      for (int jt = 0; jt < 3; ++jt) {
        #pragma unroll
        for (int mt = 0; mt < 2; ++mt) {
          v4f z = (v4f){0.f, 0.f, 0.f, 0.f};
          z = mfma16(kb[mt][0], afr[jt][0], z);
          z = mfma16(kb[mt][1], afr[jt][1], z);
          float p0 = fexp2(z[0]), p1 = fexp2(z[1]), p2 = fexp2(z[2]), p3 = fexp2(z[3]);
          psum += (p0 + p1) + (p2 + p3);
          uint2 pwv; pwv.x = cvtpk(p0, p1); pwv.y = cvtpk(p2, p3);
          *(uint2*)(Pw + ((mt*64 + l) << 3)) = pwv;   // write-linear slot
        }
        uint2 r0 = *(uint2*)(Pw + rbase);
        uint2 r1 = *(uint2*)(Pw + rbase + 128);
        uint4 pa; pa.x = r0.x; pa.y = r0.y; pa.z = r1.x; pa.w = r1.y;
        #pragma unroll
        for (int dt = 0; dt < 4; ++dt)
          racc[jt][dt] = mfma16(pa, vb[dt], racc[jt][dt]);
      }
    }

    float lsum = psum;
    #pragma unroll
    for (int off = 32; off; off >>= 1) lsum += __shfl_xor(lsum, off, 64);

    float op[4] = {0.f, 0.f, 0.f, 0.f};
    #pragma unroll
    for (int jt = 0; jt < 3; ++jt)
      #pragma unroll
      for (int dt = 0; dt < 4; ++dt) {
        op[dt] = fmaf(bf16_lo(v1f[jt*4+dt].x), racc[jt][dt][0], op[dt]);
        op[dt] = fmaf(bf16_hi(v1f[jt*4+dt].x), racc[jt][dt][1], op[dt]);
        op[dt] = fmaf(bf16_lo(v1f[jt*4+dt].y), racc[jt][dt][2], op[dt]);
        op[dt] = fmaf(bf16_hi(v1f[jt*4+dt].y), racc[jt][dt][3], op[dt]);
      }
    #pragma unroll
    for (int dt = 0; dt < 4; ++dt) {
      op[dt] += __shfl_xor(op[dt], 16, 64);
      op[dt] += __shfl_xor(op[dt], 32, 64);
    }
    if (l < 16) {
      #pragma unroll
      for (int dt = 0; dt < 4; ++dt) redF[w*64 + dt*16 + l] = op[dt];
    }
    if (l == 0) *(float*)(lds + 49152 + w*1024) = lsum;
    __syncthreads();
    if (tid < 64) {
      float o = redF[tid] + redF[64 + tid] + redF[128 + tid] + redF[192 + tid];
      float lt = *(float*)(lds + 49152) + *(float*)(lds + 49152 + 1024)
               + *(float*)(lds + 49152 + 2048) + *(float*)(lds + 49152 + 3072);
      float v = o / lt;
      // ATT in out_proj's A-frag hi/lo order (32-row tiles)
      int m_tok = b*N_ + i0 + ii;
      int mt = m_tok >> 5, mloc = m_tok & 31;
      int g = tid >> 3, e = tid & 7;
      int off = ((((mt*8 + h)*8 + g)*32 + mloc) << 3) + e;
      unsigned short hs = (unsigned short)cvtpk(v, v);
      float resid = v - __uint_as_float(((unsigned int)hs) << 16);
      unsigned short lsb = (unsigned short)cvtpk(resid, resid);
      ATThi[off] = hs; ATTlo[off] = lsb;
    }
    __syncthreads();
  }
}

// ---------- Kernel 3: output projection (all prepacked, no LDS, no barriers) ----------
// grid (16, 12): 32 cols x 32 tokens
__global__ __launch_bounds__(256)
void out_proj_kernel(const uint4* __restrict__ AHi, const uint4* __restrict__ ALo,
                     const uint4* __restrict__ WoHi, const uint4* __restrict__ WoLo,
                     float* __restrict__ out)
{
  const int bn = blockIdx.x;   // 0..15
  const int bm = blockIdx.y;   // 0..11
  const int tid = threadIdx.x;
  const int w = tid >> 6, l = tid & 63;
  const int c = l & 15, q = l >> 4;
  const int mhalf = w & 1, nhalf = w >> 1;

  v4f acc = (v4f){0,0,0,0};

  for (int kc = 0; kc < 8; ++kc) {
    #pragma unroll
    for (int kh = 0; kh < 2; ++kh) {
      int g = kh*4 + q;
      int aidx = ((bm*8 + kc)*8 + g)*32 + mhalf*16 + c;
      uint4 ah = AHi[aidx];
      uint4 al = ALo[aidx];
      int nrow = bn*32 + nhalf*16 + c;
      int bidx = (((nrow >> 6)*8 + kc)*8 + g)*64 + (nrow & 63);
      uint4 bh = WoHi[bidx];
      uint4 bl = WoLo[bidx];
      acc = mfma16(ah, bh, acc);
      acc = mfma16(ah, bl, acc);
      acc = mfma16(al, bh, acc);
    }
  }

  #pragma unroll
  for (int r = 0; r < 4; ++r) {
    int m = bm*32 + mhalf*16 + q*4 + r;
    int n = bn*32 + nhalf*16 + c;
    out[(size_t)m*DIM_ + n] = acc[r];
  }
}

// ---------- launch ----------
extern "C" void kernel_launch(void* const* d_in, const int* in_sizes, int n_in,
                              void* d_out, int out_size, void* d_ws, size_t ws_size,
                              hipStream_t stream) {
  const float* tokens = (const float*)d_in[0];
  const float* w_qkv  = (const float*)d_in[1];
  const float* w_out  = (const float*)d_in[2];
  const float* qw     = (const float*)d_in[3];
  const float* k1w    = (const float*)d_in[4];
  const float* k2w    = (const float*)d_in[5];
  const float* v1w    = (const float*)d_in[6];
  const float* v2w    = (const float*)d_in[7];
  float* out = (float*)d_out;

  float* ws = (float*)d_ws;
  // ws layout (floats), total 2359296 f = 9.44 MB:
  float* Q    = ws;                                  // 196608
  uint4* K1P  = (uint4*)(ws + 196608);               // 98304 f
  uint2* V1P  = (uint2*)(ws + 196608 + 98304);       // 98304 f
  uint4* K2P  = (uint4*)(ws + 196608 + 2*98304);     // 98304 f
  uint4* V2P  = (uint4*)(ws + 196608 + 3*98304);     // 98304 f
  uint4* AtkHi= (uint4*)(ws + 196608 + 4*98304);     // 98304 f
  uint4* AtkLo= (uint4*)(ws + 196608 + 5*98304);     // 98304 f
  uint4* WqHi = (uint4*)(ws + 196608 + 6*98304);     // 655360 f
  uint4* WqLo = (uint4*)(ws + 196608 + 6*98304 + 655360);
  uint4* WoHi = (uint4*)(ws + 196608 + 6*98304 + 2*655360);          // 131072 f
  uint4* WoLo = (uint4*)(ws + 196608 + 6*98304 + 2*655360 + 131072);
  // ATT packed aliases tokens-packed region (dead after qkv)
  unsigned short* ATThi = (unsigned short*)AtkHi;
  unsigned short* ATTlo = (unsigned short*)AtkLo;

  prepack_kernel<<<864, 256, 0, stream>>>(tokens, w_qkv, w_out,
                                          AtkHi, AtkLo, WqHi, WqLo, WoHi, WoLo);
  qkv_mfma_kernel<<<dim3(40, 12), 256, 0, stream>>>(AtkHi, AtkLo, WqHi, WqLo,
                                                    qw, k1w, k2w, v1w, v2w,
                                                    Q, K1P, V1P, K2P, V2P);
  attn_kernel<<<512, 256, 0, stream>>>(Q, K1P, V1P, K2P, V2P, ATThi, ATTlo);
  out_proj_kernel<<<dim3(16, 12), 256, 0, stream>>>((const uint4*)ATThi, (const uint4*)ATTlo,
                                                    WoHi, WoLo, out);
}